// Round 18
// baseline (80.000 us; speedup 1.0000x reference)
//
#include <hip/hip_runtime.h>

typedef unsigned short u16;
typedef unsigned int u32;
typedef __attribute__((ext_vector_type(8))) __bf16 bf16x8;
typedef __attribute__((ext_vector_type(4))) float f32x4;
typedef __attribute__((ext_vector_type(16))) float f32x16;
typedef __attribute__((ext_vector_type(4))) u32 u32x4;

#if __has_builtin(__builtin_amdgcn_exp2f)
#define EXP2F(x) __builtin_amdgcn_exp2f(x)
#else
#define EXP2F(x) exp2f(x)
#endif

// 0.125 (1/sqrt(64)) * log2(e): folded into Wq/bq so scores are in exp2 domain
#define SC_Q 0.18033688011112042f

static __device__ __forceinline__ u16 f2bf(float f) {
  unsigned u = __builtin_bit_cast(unsigned, f);
  u += 0x7fffu + ((u >> 16) & 1u);
  return (u16)(u >> 16);
}
static __device__ __forceinline__ float bf2f(u16 v) {
  return __builtin_bit_cast(float, (u32)v << 16);
}

static __device__ __forceinline__ f32x4 mfma16(bf16x8 a, bf16x8 b, f32x4 c) {
  return __builtin_amdgcn_mfma_f32_16x16x32_bf16(a, b, c, 0, 0, 0);
}
static __device__ __forceinline__ f32x16 mfma32(bf16x8 a, bf16x8 b, f32x16 c) {
  return __builtin_amdgcn_mfma_f32_32x32x16_bf16(a, b, c, 0, 0, 0);
}

static __device__ __forceinline__ u32 cvtpk(float lo, float hi_) {
  u32 r;
  asm("v_cvt_pk_bf16_f32 %0, %1, %2" : "=v"(r) : "v"(lo), "v"(hi_));
  return r;
}

static __device__ __forceinline__ void barrier_raw() {
  asm volatile("" ::: "memory");
  __builtin_amdgcn_s_barrier();
  asm volatile("" ::: "memory");
}

static __device__ __forceinline__ void gload_lds16(const u16* g, u16* l) {
  __builtin_amdgcn_global_load_lds((const __attribute__((address_space(1))) u32*)g,
                                   (__attribute__((address_space(3))) u32*)l, 16, 0, 0);
}

// ---------------- pack kernel ----------------
__global__ void pack_w_kernel(const float* __restrict__ Wq, const float* __restrict__ Wk,
                              const float* __restrict__ Wv, const float* __restrict__ Wo,
                              const float* __restrict__ bq, const float* __restrict__ bk,
                              const float* __restrict__ bv, u16* __restrict__ BTqkv,
                              u16* __restrict__ BTo, float* __restrict__ bqkv) {
  int idx = blockIdx.x * 256 + threadIdx.x;
  if (idx < 1536 * 512) {
    int n = idx >> 9, d = idx & 511;
    int t = n >> 9, rem = n & 511;
    int h = rem >> 6, e = rem & 63;
    const float* W = (t == 0) ? Wq : ((t == 1) ? Wk : Wv);
    float sc = (t == 0) ? SC_Q : 1.0f;
    BTqkv[idx] = f2bf(W[((size_t)h * 512 + d) * 64 + e] * sc);
  } else if (idx < 1536 * 512 + 512 * 512) {
    int j = idx - 1536 * 512;
    int n = j >> 9, d = j & 511;
    BTo[j] = f2bf(Wo[(size_t)d * 512 + n]);
  } else if (idx < 1536 * 512 + 512 * 512 + 1536) {
    int j = idx - (1536 * 512 + 512 * 512);
    int t = j >> 9, rem = j & 511;
    float v = (t == 0 ? bq : (t == 1 ? bk : bv))[rem];
    bqkv[j] = v * (t == 0 ? SC_Q : 1.0f);
  }
}

// ------- QKV GEMM (fused f32->bf16 A-pack), 128x64 tile; V -> Vtl + Vtp -------
// grid (x = m-tile:32, y = n-tile:24): same-m blocks share XCD -> A-panel L2 reuse.
__global__ __launch_bounds__(256) void gemm_qkv_kernel(const float* __restrict__ X,
                                                       const u16* __restrict__ BT,
                                                       const float* __restrict__ bias,
                                                       u16* __restrict__ QK,
                                                       u16* __restrict__ Vtl,
                                                       u16* __restrict__ Vtp) {
  __shared__ __align__(16) u16 Al[2][128 * 64];
  __shared__ __align__(16) u16 Bl[2][64 * 64];
  const int K = 512;
  const int tid = threadIdx.x;
  const int w = tid >> 6, lane = tid & 63, g = lane >> 4, i = lane & 15;
  const int m0 = blockIdx.x * 128, n0 = blockIdx.y * 64;
  const int wr = (w >> 1) * 64, wc = (w & 1) * 32;

  f32x4 acc[4][2];
#pragma unroll
  for (int a = 0; a < 4; ++a)
#pragma unroll
    for (int b = 0; b < 2; ++b) acc[a][b] = f32x4{0.f, 0.f, 0.f, 0.f};

  const float* xg[4];
#pragma unroll
  for (int it = 0; it < 4; ++it) {
    const int slot = it * 256 + tid;
    xg[it] = X + (size_t)(m0 + (slot >> 3)) * K + (slot & 7) * 8;
  }
  const u16* bgp[2];
#pragma unroll
  for (int it = 0; it < 2; ++it) {
    const int slot = it * 256 + tid;
    bgp[it] = BT + (size_t)(n0 + (slot >> 3)) * K + (slot & 7) * 8;
  }

  float4 a0[4], a1[4];
#pragma unroll
  for (int it = 0; it < 4; ++it) {
    a0[it] = *reinterpret_cast<const float4*>(xg[it]);
    a1[it] = *reinterpret_cast<const float4*>(xg[it] + 4);
  }
#pragma unroll
  for (int it = 0; it < 2; ++it) gload_lds16(bgp[it], &Bl[0][(it * 256 + tid) * 8]);
  asm volatile("s_waitcnt vmcnt(2)" ::: "memory");
#pragma unroll
  for (int it = 0; it < 4; ++it) {
    u32x4 pk = {cvtpk(a0[it].x, a0[it].y), cvtpk(a0[it].z, a0[it].w),
                cvtpk(a1[it].x, a1[it].y), cvtpk(a1[it].z, a1[it].w)};
    *reinterpret_cast<u32x4*>(&Al[0][(it * 256 + tid) * 8]) = pk;
  }
  asm volatile("s_waitcnt lgkmcnt(0)" ::: "memory");

  int cur = 0;
  for (int t = 0; t < 8; ++t) {
    const int k0 = t * 64;
    if (t < 7) {
#pragma unroll
      for (int it = 0; it < 4; ++it) {
        a0[it] = *reinterpret_cast<const float4*>(xg[it] + k0 + 64);
        a1[it] = *reinterpret_cast<const float4*>(xg[it] + k0 + 68);
      }
#pragma unroll
      for (int it = 0; it < 2; ++it)
        gload_lds16(bgp[it] + k0 + 64, &Bl[cur ^ 1][(it * 256 + tid) * 8]);
      asm volatile("s_waitcnt vmcnt(10)" ::: "memory");
    } else {
      asm volatile("s_waitcnt vmcnt(0)" ::: "memory");
    }
    barrier_raw();
#pragma unroll
    for (int ks = 0; ks < 2; ++ks) {
      bf16x8 af[4], bf[2];
#pragma unroll
      for (int mf = 0; mf < 4; ++mf)
        af[mf] = *reinterpret_cast<const bf16x8*>(
            &Al[cur][(wr + mf * 16 + i) * 64 + ks * 32 + 8 * g]);
#pragma unroll
      for (int nf = 0; nf < 2; ++nf)
        bf[nf] = *reinterpret_cast<const bf16x8*>(
            &Bl[cur][(wc + nf * 16 + i) * 64 + ks * 32 + 8 * g]);
#pragma unroll
      for (int mf = 0; mf < 4; ++mf)
#pragma unroll
        for (int nf = 0; nf < 2; ++nf) acc[mf][nf] = mfma16(af[mf], bf[nf], acc[mf][nf]);
    }
    if (t < 7) {
      asm volatile("s_waitcnt vmcnt(2)" ::: "memory");
#pragma unroll
      for (int it = 0; it < 4; ++it) {
        u32x4 pk = {cvtpk(a0[it].x, a0[it].y), cvtpk(a0[it].z, a0[it].w),
                    cvtpk(a1[it].x, a1[it].y), cvtpk(a1[it].z, a1[it].w)};
        *reinterpret_cast<u32x4*>(&Al[cur ^ 1][(it * 256 + tid) * 8]) = pk;
      }
      asm volatile("s_waitcnt lgkmcnt(0)" ::: "memory");
    }
    barrier_raw();
    cur ^= 1;
  }

  if (n0 < 1024) {
#pragma unroll
    for (int nf = 0; nf < 2; ++nf) {
      const int col = n0 + wc + nf * 16 + i;
      const float bb = bias[col];
#pragma unroll
      for (int mf = 0; mf < 4; ++mf) {
#pragma unroll
        for (int r = 0; r < 4; ++r) {
          const int row = m0 + wr + mf * 16 + 4 * g + r;
          QK[(size_t)row * 1024 + col] = f2bf(acc[mf][nf][r] + bb);
        }
      }
    }
  } else {
    const int b = m0 >> 10;
    const int s0b = (m0 & 1023) + wr;
#pragma unroll
    for (int nf = 0; nf < 2; ++nf) {
      const int col = n0 + wc + nf * 16 + i;
      const float bb = bias[col];
      const int vcol = col - 1024;
      const int hh = vcol >> 6;
      const int hmm = (hh < 4) ? hh : 4;
      const int Mlog = hmm + 1;
      const int NcH = 1024 >> Mlog;
      const size_t rowb = (size_t)(b * 512 + vcol) * 1024;
#pragma unroll
      for (int mf = 0; mf < 4; ++mf) {
        u16 pk[4];
#pragma unroll
        for (int r = 0; r < 4; ++r) pk[r] = f2bf(acc[mf][nf][r] + bb);
        const int ss = s0b + mf * 16 + 4 * g;
        *reinterpret_cast<uint2*>(&Vtl[rowb + ss]) = *reinterpret_cast<const uint2*>(pk);
#pragma unroll
        for (int r = 0; r < 4; ++r) {
          const int seq = ss + r;
          const int pidx = (seq & ((1 << Mlog) - 1)) * NcH + (seq >> Mlog);
          Vtp[rowb + pidx] = pk[r];
        }
      }
    }
  }
}

// ---------------- DENSE attention, heads 0-3, 2-way KV split, KVBLK=64 ----------------
// grid (4 h, 8 qt, 8 zz=b*2+s); block keys [s*512, s*512+512); writes slot s
__global__ __launch_bounds__(256) void attn3_kernel(const u16* __restrict__ QK,
                                                    const u16* __restrict__ Vt,
                                                    u16* __restrict__ Opart16,
                                                    float* __restrict__ mlpart) {
  __shared__ __align__(16) u16 Kl[2][4096];
  __shared__ __align__(16) u16 Vl[2][4096];

  const int tid = threadIdx.x;
  const int w = tid >> 6, lane = tid & 63;
  const int col = lane & 31, hi = lane >> 5;
  const int h = blockIdx.x;  // 0..3
  const int zz = blockIdx.z;
  const int b = zz >> 1, s = zz & 1;
  const int bh = b * 8 + h;
  const int q0w = blockIdx.y * 128 + w * 32;
  const int kvlo = s * 512;
  const int hm = (h < 4) ? h : 4;
  const int band = 1 << hm;
  const int modm = (2 << hm) - 1;
  const int qrow = q0w + col;

  bf16x8 qf[4];
  const size_t qoff = (size_t)(b * 1024 + qrow) * 1024 + h * 64 + 8 * hi;
#pragma unroll
  for (int et = 0; et < 4; ++et)
    qf[et] = *reinterpret_cast<const bf16x8*>(QK + qoff + 16 * et);

  float bias[16];
#pragma unroll
  for (int r = 0; r < 16; ++r) {
    int c = (r & 3) + 8 * (r >> 2) + 4 * hi;
    bias[r] = (((qrow - c) & modm) == 0) ? 0.f : -1e30f;
  }

  f32x16 accO0 = {}, accO1 = {};
  float m_run = -1e30f, l_run = 0.f;

  const int slot0 = tid, slot1 = tid + 256;
  const int kj0 = slot0 >> 3, keb0 = (slot0 & 7) ^ (kj0 & 7);
  const int kj1 = slot1 >> 3, keb1 = (slot1 & 7) ^ (kj1 & 7);
  const u16* kg0 = QK + (size_t)(b * 1024 + kj0) * 1024 + 512 + h * 64 + keb0 * 8;
  const u16* kg1 = QK + (size_t)(b * 1024 + kj1) * 1024 + 512 + h * 64 + keb1 * 8;
  const u16* vg0 = Vt + (size_t)(bh * 64 + kj0) * 1024 + keb0 * 8;
  const u16* vg1 = Vt + (size_t)(bh * 64 + kj1) * 1024 + keb1 * 8;

#define STAGE3(bi, kv0)                                                 \
  do {                                                                  \
    gload_lds16(kg0 + (size_t)(kv0) * 1024, &Kl[bi][slot0 * 8]);        \
    gload_lds16(kg1 + (size_t)(kv0) * 1024, &Kl[bi][slot1 * 8]);        \
    gload_lds16(vg0 + (kv0), &Vl[bi][slot0 * 8]);                       \
    gload_lds16(vg1 + (kv0), &Vl[bi][slot1 * 8]);                       \
  } while (0)

  STAGE3(0, kvlo);
  int buf = 0;

  for (int t = 0; t < 8; ++t) {
    const int kv0 = kvlo + t * 64;
    if (t < 7) {
      STAGE3(buf ^ 1, kv0 + 64);
      asm volatile("s_waitcnt vmcnt(4)" ::: "memory");
    } else {
      asm volatile("s_waitcnt vmcnt(0)" ::: "memory");
    }
    barrier_raw();

    const u16* Kb = Kl[buf];
    const u16* Vb = Vl[buf];

    f32x16 s0 = {}, s1 = {};
    __builtin_amdgcn_s_setprio(1);
#pragma unroll
    for (int et = 0; et < 4; ++et) {
      const int sw = ((2 * et + hi) ^ (col & 7)) << 3;
      bf16x8 kf0 = *reinterpret_cast<const bf16x8*>(&Kb[col * 64 + sw]);
      bf16x8 kf1 = *reinterpret_cast<const bf16x8*>(&Kb[(col + 32) * 64 + sw]);
      s0 = mfma32(kf0, qf[et], s0);
      s1 = mfma32(kf1, qf[et], s1);
    }
    __builtin_amdgcn_s_setprio(0);

    float p[32];
    const int dq = qrow - kv0;
    const bool near = (q0w <= kv0 + 63 + band) && (kv0 <= q0w + 31 + band);
    if (near) {
#pragma unroll
      for (int r = 0; r < 16; ++r) {
        const int c = (r & 3) + 8 * (r >> 2) + 4 * hi;
        int d0 = dq - c, d1 = d0 - 32;
        d0 = d0 < 0 ? -d0 : d0;
        d1 = d1 < 0 ? -d1 : d1;
        p[r] = (d0 <= band) ? s0[r] : s0[r] + bias[r];
        p[r + 16] = (d1 <= band) ? s1[r] : s1[r] + bias[r];
      }
    } else {
#pragma unroll
      for (int r = 0; r < 16; ++r) {
        p[r] = s0[r] + bias[r];
        p[r + 16] = s1[r] + bias[r];
      }
    }

    float tr[16];
#pragma unroll
    for (int j = 0; j < 16; ++j) tr[j] = fmaxf(p[j], p[j + 16]);
#pragma unroll
    for (int st = 8; st >= 1; st >>= 1)
#pragma unroll
      for (int j = 0; j < st; ++j) tr[j] = fmaxf(tr[j], tr[j + st]);
    float mu = fmaxf(tr[0], __shfl_xor(tr[0], 32));

    if (__any(mu > m_run + 8.f)) {
      float mn = fmaxf(m_run, mu);
      float corr = EXP2F(m_run - mn);
      m_run = mn;
      l_run *= corr;
#pragma unroll
      for (int j = 0; j < 16; ++j) {
        accO0[j] *= corr;
        accO1[j] *= corr;
      }
    }

#pragma unroll
    for (int j = 0; j < 32; ++j) p[j] = EXP2F(p[j] - m_run);
    float ts[16];
#pragma unroll
    for (int j = 0; j < 16; ++j) ts[j] = p[j] + p[j + 16];
#pragma unroll
    for (int st = 8; st >= 1; st >>= 1)
#pragma unroll
      for (int j = 0; j < st; ++j) ts[j] += ts[j + st];
    l_run += ts[0] + __shfl_xor(ts[0], 32);

#pragma unroll
    for (int kt = 0; kt < 4; ++kt) {
      const float* pp = (kt < 2) ? p : p + 16;
      const int R = (kt & 1) * 8;
      u32 A0 = cvtpk(pp[R + 0], pp[R + 1]);
      u32 A1 = cvtpk(pp[R + 2], pp[R + 3]);
      u32 B0 = cvtpk(pp[R + 4], pp[R + 5]);
      u32 B1 = cvtpk(pp[R + 6], pp[R + 7]);
      u32 t0 = __shfl_xor(hi ? A0 : B0, 32);
      u32 t1 = __shfl_xor(hi ? A1 : B1, 32);
      u32 w0 = hi ? t0 : A0;
      u32 w1 = hi ? t1 : A1;
      u32 w2 = hi ? B0 : t0;
      u32 w3 = hi ? B1 : t1;
      u32x4 pu = {w0, w1, w2, w3};
      bf16x8 paf = __builtin_bit_cast(bf16x8, pu);
      const int jb = 2 * kt + hi;
      __builtin_amdgcn_s_setprio(1);
      {
        const int erow = col;
        bf16x8 vf = *reinterpret_cast<const bf16x8*>(&Vb[erow * 64 + ((jb ^ (erow & 7)) << 3)]);
        accO0 = mfma32(paf, vf, accO0);
      }
      {
        const int erow = 32 + col;
        bf16x8 vf = *reinterpret_cast<const bf16x8*>(&Vb[erow * 64 + ((jb ^ (erow & 7)) << 3)]);
        accO1 = mfma32(paf, vf, accO1);
      }
      __builtin_amdgcn_s_setprio(0);
    }

    barrier_raw();
    buf ^= 1;
  }
#undef STAGE3

  const size_t obase = (size_t)(s * 32 + bh) * 1024 + q0w;
  if (lane < 32) {
    float2 ml2 = {m_run, l_run};
    *reinterpret_cast<float2*>(&mlpart[(obase + col) * 2]) = ml2;
  }
#pragma unroll
  for (int r = 0; r < 16; ++r) {
    const int c = (r & 3) + 8 * (r >> 2) + 4 * hi;
    u16* orow = Opart16 + (obase + c) * 64;
    orow[col] = f2bf(accO0[r]);
    orow[32 + col] = f2bf(accO1[r]);
  }
}

// ---------------- Phase D: dilated, heads 4-7 (M=32, Nc=32), PER-WAVE tiles ----------------
// grid (4, 8, 4); h = 4 + blockIdx.x; wave w owns class cls = qblk*4 + w; writes slot 1
__global__ __launch_bounds__(256) void attnD_kernel(const u16* __restrict__ QK,
                                                    const u16* __restrict__ Vtp,
                                                    u16* __restrict__ Opart16,
                                                    float* __restrict__ mlpart) {
  __shared__ __align__(16) u16 Kl[4][32 * 72];  // per-wave: [kj 0..31][e], stride 72
  __shared__ __align__(16) u16 Vl[4][64 * 40];  // per-wave: [e][key 0..31], stride 40

  const int tid = threadIdx.x;
  const int w = tid >> 6, lane = tid & 63;
  const int col = lane & 31, hi = lane >> 5;
  const int h = 4 + blockIdx.x;
  const int qblk = blockIdx.y, b = blockIdx.z;
  const int M = 32;
  const int cls = qblk * 4 + w;  // this wave's residue class (0..31)
  const int bh = b * 8 + h;

  // per-wave K staging: 32 rows x 8 eb-blocks = 256 slots over 64 lanes
  for (int sl = lane; sl < 256; sl += 64) {
    const int kj = sl >> 3, eb = sl & 7;
    const int physk = cls + kj * M;
    bf16x8 kreg = *reinterpret_cast<const bf16x8*>(
        QK + (size_t)(b * 1024 + physk) * 1024 + 512 + h * 64 + eb * 8);
    *reinterpret_cast<bf16x8*>(&Kl[w][kj * 72 + eb * 8]) = kreg;
  }
  // per-wave V staging: 64 e-rows x 4 key-blocks = 256 slots
  for (int sl = lane; sl < 256; sl += 64) {
    const int e = sl >> 2, tb = sl & 3;
    bf16x8 vreg = *reinterpret_cast<const bf16x8*>(
        Vtp + (size_t)(b * 512 + h * 64 + e) * 1024 + cls * 32 + tb * 8);
    *reinterpret_cast<bf16x8*>(&Vl[w][e * 40 + tb * 8]) = vreg;
  }

  const int physq = cls + col * M;
  bf16x8 qf[4];
  const size_t qoff = (size_t)(b * 1024 + physq) * 1024 + h * 64 + 8 * hi;
#pragma unroll
  for (int et = 0; et < 4; ++et)
    qf[et] = *reinterpret_cast<const bf16x8*>(QK + qoff + 16 * et);

  __syncthreads();

  f32x16 s0 = {};
  __builtin_amdgcn_s_setprio(1);
#pragma unroll
  for (int et = 0; et < 4; ++et) {
    const int sw8 = (2 * et + hi) * 8;
    bf16x8 kf0 = *reinterpret_cast<const bf16x8*>(&Kl[w][col * 72 + sw8]);
    s0 = mfma32(kf0, qf[et], s0);
  }
  __builtin_amdgcn_s_setprio(0);

  float p[32];
#pragma unroll
  for (int r = 0; r < 16; ++r) {
    p[r] = s0[r];
    p[r + 16] = -1e30f;  // keys 32..63 don't exist (Nc=32)
  }
  float tr[16];
#pragma unroll
  for (int j = 0; j < 16; ++j) tr[j] = fmaxf(p[j], p[j + 16]);
#pragma unroll
  for (int st = 8; st >= 1; st >>= 1)
#pragma unroll
    for (int j = 0; j < st; ++j) tr[j] = fmaxf(tr[j], tr[j + st]);
  const float mu = fmaxf(tr[0], __shfl_xor(tr[0], 32));

#pragma unroll
  for (int j = 0; j < 32; ++j) p[j] = EXP2F(p[j] - mu);
  float ts[16];
#pragma unroll
  for (int j = 0; j < 16; ++j) ts[j] = p[j] + p[j + 16];
#pragma unroll
  for (int st = 8; st >= 1; st >>= 1)
#pragma unroll
    for (int j = 0; j < st; ++j) ts[j] += ts[j + st];
  const float l = ts[0] + __shfl_xor(ts[0], 32);

  f32x16 accO0 = {}, accO1 = {};
  const u16* Vb = &Vl[w][0];
#pragma unroll
  for (int kt = 0; kt < 2; ++kt) {
    const float* pp = p;
    const int R = (kt & 1) * 8;
    u32 A0 = cvtpk(pp[R + 0], pp[R + 1]);
    u32 A1 = cvtpk(pp[R + 2], pp[R + 3]);
    u32 B0 = cvtpk(pp[R + 4], pp[R + 5]);
    u32 B1 = cvtpk(pp[R + 6], pp[R + 7]);
    u32 t0 = __shfl_xor(hi ? A0 : B0, 32);
    u32 t1 = __shfl_xor(hi ? A1 : B1, 32);
    u32 w0 = hi ? t0 : A0;
    u32 w1 = hi ? t1 : A1;
    u32 w2 = hi ? B0 : t0;
    u32 w3 = hi ? B1 : t1;
    u32x4 pu = {w0, w1, w2, w3};
    bf16x8 paf = __builtin_bit_cast(bf16x8, pu);
    const int jb = 2 * kt + hi;  // 0..3 -> keys 0..31
    __builtin_amdgcn_s_setprio(1);
    {
      const int erow = col;
      bf16x8 vf = *reinterpret_cast<const bf16x8*>(&Vb[erow * 40 + (jb << 3)]);
      accO0 = mfma32(paf, vf, accO0);
    }
    {
      const int erow = 32 + col;
      bf16x8 vf = *reinterpret_cast<const bf16x8*>(&Vb[erow * 40 + (jb << 3)]);
      accO1 = mfma32(paf, vf, accO1);
    }
    __builtin_amdgcn_s_setprio(0);
  }

  // epilogue: slot 1
  const size_t pb = (size_t)(1 * 32 + bh) * 1024;
  if (lane < 32) {
    float2 ml2 = {mu, l};
    *reinterpret_cast<float2*>(&mlpart[(pb + physq) * 2]) = ml2;
  }
#pragma unroll
  for (int r = 0; r < 16; ++r) {
    const int cf = (r & 3) + 8 * (r >> 2) + 4 * hi;
    const int physr = cls + cf * M;
    u16* orow = Opart16 + (pb + physr) * 64;
    orow[col] = f2bf(accO0[r]);
    orow[32 + col] = f2bf(accO1[r]);
  }
}

// ---------------- Phase B: band, heads 4-7 only (band=16) ----------------
// grid (4, 8, 4); h = 4 + blockIdx.x; writes slot 0
__global__ __launch_bounds__(256) void attnB_kernel(const u16* __restrict__ QK,
                                                    const u16* __restrict__ Vtl,
                                                    u16* __restrict__ Opart16,
                                                    float* __restrict__ mlpart) {
  __shared__ __align__(16) u16 Kl[4][64 * 72];
  __shared__ __align__(16) u16 Vl[4][64 * 72];

  const int tid = threadIdx.x;
  const int w = tid >> 6, lane = tid & 63;
  const int col = lane & 31, hi = lane >> 5;
  const int h = 4 + blockIdx.x;
  const int qt = blockIdx.y, b = blockIdx.z;
  const int bh = b * 8 + h;
  const int band = 16;
  const int q0w = qt * 128 + w * 32;
  const int qrow = q0w + col;
  int kw = q0w - 16;
  kw = kw < 0 ? 0 : (kw > 960 ? 960 : kw);

  for (int sl = tid; sl < 2048; sl += 256) {
    const int wv = sl >> 9, s9 = sl & 511;
    int kwv = qt * 128 + wv * 32 - 16;
    kwv = kwv < 0 ? 0 : (kwv > 960 ? 960 : kwv);
    const int kj = s9 >> 3, eb = s9 & 7;
    bf16x8 kreg = *reinterpret_cast<const bf16x8*>(
        QK + (size_t)(b * 1024 + kwv + kj) * 1024 + 512 + h * 64 + eb * 8);
    *reinterpret_cast<bf16x8*>(&Kl[wv][kj * 72 + eb * 8]) = kreg;
    bf16x8 vreg = *reinterpret_cast<const bf16x8*>(
        Vtl + (size_t)(b * 512 + h * 64 + kj) * 1024 + kwv + eb * 8);
    *reinterpret_cast<bf16x8*>(&Vl[wv][kj * 72 + eb * 8]) = vreg;
  }

  bf16x8 qf[4];
  const size_t qoff = (size_t)(b * 1024 + qrow) * 1024 + h * 64 + 8 * hi;
#pragma unroll
  for (int et = 0; et < 4; ++et)
    qf[et] = *reinterpret_cast<const bf16x8*>(QK + qoff + 16 * et);

  f32x16 accO0 = {}, accO1 = {};

  __syncthreads();

  const u16* Kb = &Kl[w][0];
  const u16* Vb = &Vl[w][0];

  f32x16 s0 = {}, s1 = {};
  __builtin_amdgcn_s_setprio(1);
#pragma unroll
  for (int et = 0; et < 4; ++et) {
    const int sw8 = (2 * et + hi) * 8;
    bf16x8 kf0 = *reinterpret_cast<const bf16x8*>(&Kb[col * 72 + sw8]);
    bf16x8 kf1 = *reinterpret_cast<const bf16x8*>(&Kb[(col + 32) * 72 + sw8]);
    s0 = mfma32(kf0, qf[et], s0);
    s1 = mfma32(kf1, qf[et], s1);
  }
  __builtin_amdgcn_s_setprio(0);

  float p[32];
  const int dq = qrow - kw;
#pragma unroll
  for (int r = 0; r < 16; ++r) {
    const int cf = (r & 3) + 8 * (r >> 2) + 4 * hi;
    const int d0 = dq - cf, d1 = d0 - 32;
    const int a0 = d0 < 0 ? -d0 : d0;
    const int a1 = d1 < 0 ? -d1 : d1;
    p[r] = (a0 >= 1 && a0 <= band) ? s0[r] : -1e30f;
    p[r + 16] = (a1 >= 1 && a1 <= band) ? s1[r] : -1e30f;
  }

  float tr[16];
#pragma unroll
  for (int j = 0; j < 16; ++j) tr[j] = fmaxf(p[j], p[j + 16]);
#pragma unroll
  for (int st = 8; st >= 1; st >>= 1)
#pragma unroll
    for (int j = 0; j < st; ++j) tr[j] = fmaxf(tr[j], tr[j + st]);
  const float mu = fmaxf(tr[0], __shfl_xor(tr[0], 32));

#pragma unroll
  for (int j = 0; j < 32; ++j) p[j] = EXP2F(p[j] - mu);
  float ts[16];
#pragma unroll
  for (int j = 0; j < 16; ++j) ts[j] = p[j] + p[j + 16];
#pragma unroll
  for (int st = 8; st >= 1; st >>= 1)
#pragma unroll
    for (int j = 0; j < st; ++j) ts[j] += ts[j + st];
  const float l = ts[0] + __shfl_xor(ts[0], 32);

#pragma unroll
  for (int kt = 0; kt < 4; ++kt) {
    const float* pp = (kt < 2) ? p : p + 16;
    const int R = (kt & 1) * 8;
    u32 A0 = cvtpk(pp[R + 0], pp[R + 1]);
    u32 A1 = cvtpk(pp[R + 2], pp[R + 3]);
    u32 B0 = cvtpk(pp[R + 4], pp[R + 5]);
    u32 B1 = cvtpk(pp[R + 6], pp[R + 7]);
    u32 t0 = __shfl_xor(hi ? A0 : B0, 32);
    u32 t1 = __shfl_xor(hi ? A1 : B1, 32);
    u32 w0 = hi ? t0 : A0;
    u32 w1 = hi ? t1 : A1;
    u32 w2 = hi ? B0 : t0;
    u32 w3 = hi ? B1 : t1;
    u32x4 pu = {w0, w1, w2, w3};
    bf16x8 paf = __builtin_bit_cast(bf16x8, pu);
    const int jb = 2 * kt + hi;
    __builtin_amdgcn_s_setprio(1);
    {
      const int erow = col;
      bf16x8 vf = *reinterpret_cast<const bf16x8*>(&Vb[erow * 72 + (jb << 3)]);
      accO0 = mfma32(paf, vf, accO0);
    }
    {
      const int erow = 32 + col;
      bf16x8 vf = *reinterpret_cast<const bf16x8*>(&Vb[erow * 72 + (jb << 3)]);
      accO1 = mfma32(paf, vf, accO1);
    }
    __builtin_amdgcn_s_setprio(0);
  }

  const size_t pb = (size_t)bh * 1024;
  if (lane < 32) {
    float2 ml2 = {mu, l};
    *reinterpret_cast<float2*>(&mlpart[(pb + qrow) * 2]) = ml2;
  }
#pragma unroll
  for (int r = 0; r < 16; ++r) {
    const int cf = (r & 3) + 8 * (r >> 2) + 4 * hi;
    u16* orow = Opart16 + (pb + q0w + cf) * 64;
    orow[col] = f2bf(accO0[r]);
    orow[32 + col] = f2bf(accO1[r]);
  }
}

// ------- out projection with FUSED 2-way combine: out = combine(Opart,ml) @ BTo^T + bo -------
// 64x64 tile, grid (x = m-tile:64, y = n-tile:8): same-m blocks share XCD.
// h<4 rows: merges dense splits 0+1; h>=4 rows: merges B(0)+D(1). Same formula.
__global__ __launch_bounds__(256) void gemm_out_kernel(const u16* __restrict__ Opart16,
                                                       const float* __restrict__ mlpart,
                                                       const u16* __restrict__ BT,
                                                       const float* __restrict__ bias,
                                                       float* __restrict__ Cf) {
  __shared__ __align__(16) u16 Al[2][64 * 64];
  __shared__ __align__(16) u16 Bl[2][64 * 64];
  const int K = 512;
  const int tid = threadIdx.x;
  const int w = tid >> 6, lane = tid & 63, g = lane >> 4, i = lane & 15;
  const int m0 = blockIdx.x * 64, n0 = blockIdx.y * 64;
  const int wr = (w >> 1) * 32, wc = (w & 1) * 32;

  f32x4 acc[2][2];
#pragma unroll
  for (int a = 0; a < 2; ++a)
#pragma unroll
    for (int b = 0; b < 2; ++b) acc[a][b] = f32x4{0.f, 0.f, 0.f, 0.f};

  size_t R0[2];
  int cb8[2];
#pragma unroll
  for (int it = 0; it < 2; ++it) {
    const int slot = it * 256 + tid;
    const int r_in = slot >> 3;
    cb8[it] = (slot & 7) * 8;
    const int grow = m0 + r_in;
    const int b2 = grow >> 10, qr = grow & 1023;
    R0[it] = (size_t)(b2 * 8) * 1024 + qr;  // + (s2*32 + t)*1024
  }
  const u16* bgp[2];
#pragma unroll
  for (int it = 0; it < 2; ++it) {
    const int slot = it * 256 + tid;
    bgp[it] = BT + (size_t)(n0 + (slot >> 3)) * K + (slot & 7) * 8;
  }

  uint4 aO[2][2];
  float2 aml[2][2];

#define LOAD_A(t)                                                                     \
  do {                                                                                \
    _Pragma("unroll") for (int it = 0; it < 2; ++it) {                                \
      _Pragma("unroll") for (int s2 = 0; s2 < 2; ++s2) {                              \
        const size_t rb = R0[it] + (size_t)(s2 * 32 + (t)) * 1024;                    \
        aO[it][s2] = *reinterpret_cast<const uint4*>(&Opart16[rb * 64 + cb8[it]]);    \
        aml[it][s2] = *reinterpret_cast<const float2*>(&mlpart[rb * 2]);              \
      }                                                                               \
    }                                                                                 \
  } while (0)

#define COMBINE_WRITE(bi)                                                             \
  do {                                                                                \
    _Pragma("unroll") for (int it = 0; it < 2; ++it) {                                \
      const float mA = aml[it][0].x, lA = aml[it][0].y;                               \
      const float mB = aml[it][1].x, lB = aml[it][1].y;                               \
      const float M2 = fmaxf(mA, mB);                                                 \
      const float wA = EXP2F(mA - M2), wB = EXP2F(mB - M2);                           \
      const float inv = 1.0f / (lA * wA + lB * wB);                                   \
      const float sA = wA * inv, sB = wB * inv;                                       \
      const u32* oa = reinterpret_cast<const u32*>(&aO[it][0]);                       \
      const u32* ob = reinterpret_cast<const u32*>(&aO[it][1]);                       \
      float c[8];                                                                     \
      _Pragma("unroll") for (int q = 0; q < 4; ++q) {                                 \
        c[2 * q] = bf2f((u16)(oa[q] & 0xffff)) * sA + bf2f((u16)(ob[q] & 0xffff)) * sB; \
        c[2 * q + 1] = bf2f((u16)(oa[q] >> 16)) * sA + bf2f((u16)(ob[q] >> 16)) * sB; \
      }                                                                               \
      u32x4 pk = {cvtpk(c[0], c[1]), cvtpk(c[2], c[3]), cvtpk(c[4], c[5]),            \
                  cvtpk(c[6], c[7])};                                                 \
      *reinterpret_cast<u32x4*>(&Al[bi][(it * 256 + tid) * 8]) = pk;                  \
    }                                                                                 \
  } while (0)

  // prologue: A(t=0) regs + B(k0=0) glds
  LOAD_A(0);
#pragma unroll
  for (int it = 0; it < 2; ++it) gload_lds16(bgp[it], &Bl[0][(it * 256 + tid) * 8]);
  asm volatile("s_waitcnt vmcnt(2)" ::: "memory");  // 8 A-group loads done (2 B flying)
  COMBINE_WRITE(0);
  asm volatile("s_waitcnt lgkmcnt(0)" ::: "memory");

  int cur = 0;
  for (int t = 0; t < 8; ++t) {
    if (t < 7) {
      LOAD_A(t + 1);
#pragma unroll
      for (int it = 0; it < 2; ++it)
        gload_lds16(bgp[it] + t * 64 + 64, &Bl[cur ^ 1][(it * 256 + tid) * 8]);
      asm volatile("s_waitcnt vmcnt(10)" ::: "memory");  // cur B done; 8A+2B in flight
    } else {
      asm volatile("s_waitcnt vmcnt(0)" ::: "memory");
    }
    barrier_raw();
#pragma unroll
    for (int ks = 0; ks < 2; ++ks) {
      bf16x8 af[2], bf[2];
#pragma unroll
      for (int mf = 0; mf < 2; ++mf)
        af[mf] = *reinterpret_cast<const bf16x8*>(
            &Al[cur][(wr + mf * 16 + i) * 64 + ks * 32 + 8 * g]);
#pragma unroll
      for (int nf = 0; nf < 2; ++nf)
        bf[nf] = *reinterpret_cast<const bf16x8*>(
            &Bl[cur][(wc + nf * 16 + i) * 64 + ks * 32 + 8 * g]);
#pragma unroll
      for (int mf = 0; mf < 2; ++mf)
#pragma unroll
        for (int nf = 0; nf < 2; ++nf) acc[mf][nf] = mfma16(af[mf], bf[nf], acc[mf][nf]);
    }
    if (t < 7) {
      asm volatile("s_waitcnt vmcnt(2)" ::: "memory");  // A(t+1) regs landed
      COMBINE_WRITE(cur ^ 1);
      asm volatile("s_waitcnt lgkmcnt(0)" ::: "memory");
    }
    barrier_raw();
    cur ^= 1;
  }
#undef LOAD_A
#undef COMBINE_WRITE

#pragma unroll
  for (int nf = 0; nf < 2; ++nf) {
    const int col = n0 + wc + nf * 16 + i;
    const float bb = bias[col];
#pragma unroll
    for (int mf = 0; mf < 2; ++mf) {
#pragma unroll
      for (int r = 0; r < 4; ++r) {
        const int row = m0 + wr + mf * 16 + 4 * g + r;
        Cf[(size_t)row * 512 + col] = acc[mf][nf][r] + bb;
      }
    }
  }
}

// ---------------- launch ----------------
extern "C" void kernel_launch(void* const* d_in, const int* in_sizes, int n_in,
                              void* d_out, int out_size, void* d_ws, size_t ws_size,
                              hipStream_t stream) {
  const float* x = (const float*)d_in[0];
  const float* Wq = (const float*)d_in[1];
  const float* bq = (const float*)d_in[2];
  const float* Wk = (const float*)d_in[3];
  const float* bk = (const float*)d_in[4];
  const float* Wv = (const float*)d_in[5];
  const float* bv = (const float*)d_in[6];
  const float* Wo = (const float*)d_in[7];
  const float* bo = (const float*)d_in[8];
  float* out = (float*)d_out;

  char* ws = (char*)d_ws;
  u16* BTqkv = (u16*)(ws + (4u << 20));     // 1.5 MB [1536][512]
  u16* BTo = (u16*)(ws + (6u << 20));       // 0.5 MB [512][512]
  float* bqkv = (float*)(ws + (7u << 20));  // 6 KB
  u16* QK = (u16*)(ws + (8u << 20));        // 8 MB  [4096][1024] (Q | K)
  u16* Vtl = (u16*)(ws + (21u << 20));      // 4 MB  [b*512+e][seq]
  u16* Vtp = (u16*)(ws + (25u << 20));      // 4 MB  residue-permuted V^T
  u16* Opart16 = (u16*)(ws + (32u << 20));  // 8 MB  [2 slots][32 bh][1024][64]
  float* mlpart = (float*)(ws + (56u << 20));  // 512 KB [2 slots][32 bh][1024][2]

  const int NW = 1536 * 512 + 512 * 512 + 1536;
  pack_w_kernel<<<(NW + 255) / 256, 256, 0, stream>>>(Wq, Wk, Wv, Wo, bq, bk, bv, BTqkv,
                                                      BTo, bqkv);

  // QKV projection (V -> linear + residue-permuted transposed)
  gemm_qkv_kernel<<<dim3(32, 24), 256, 0, stream>>>(x, BTqkv, bqkv, QK, Vtl, Vtp);

  // heads 0-3: dense 2-way-split attention (slots 0,1)
  attn3_kernel<<<dim3(4, 8, 8), 256, 0, stream>>>(QK, Vtl, Opart16, mlpart);
  // heads 4-7: sparse D (slot 1, per-wave class tiles) + band B (slot 0)
  attnD_kernel<<<dim3(4, 8, 4), 256, 0, stream>>>(QK, Vtp, Opart16, mlpart);
  attnB_kernel<<<dim3(4, 8, 4), 256, 0, stream>>>(QK, Vtl, Opart16, mlpart);

  // output projection with fused 2-way combine (works for both head groups)
  gemm_out_kernel<<<dim3(64, 8), 256, 0, stream>>>(Opart16, mlpart, BTo, bo, out);
}

// Round 19
// 63.559 us; speedup vs baseline: 1.2587x; 1.2587x over previous
//
#include <hip/hip_runtime.h>

typedef unsigned short u16;
typedef unsigned int u32;
typedef __attribute__((ext_vector_type(8))) __bf16 bf16x8;
typedef __attribute__((ext_vector_type(4))) float f32x4;
typedef __attribute__((ext_vector_type(16))) float f32x16;
typedef __attribute__((ext_vector_type(4))) u32 u32x4;

#if __has_builtin(__builtin_amdgcn_exp2f)
#define EXP2F(x) __builtin_amdgcn_exp2f(x)
#else
#define EXP2F(x) exp2f(x)
#endif

// 0.125 (1/sqrt(64)) * log2(e): folded into Wq/bq so scores are in exp2 domain
#define SC_Q 0.18033688011112042f

static __device__ __forceinline__ u16 f2bf(float f) {
  unsigned u = __builtin_bit_cast(unsigned, f);
  u += 0x7fffu + ((u >> 16) & 1u);
  return (u16)(u >> 16);
}
static __device__ __forceinline__ float bf2f(u16 v) {
  return __builtin_bit_cast(float, (u32)v << 16);
}

static __device__ __forceinline__ f32x4 mfma16(bf16x8 a, bf16x8 b, f32x4 c) {
  return __builtin_amdgcn_mfma_f32_16x16x32_bf16(a, b, c, 0, 0, 0);
}
static __device__ __forceinline__ f32x16 mfma32(bf16x8 a, bf16x8 b, f32x16 c) {
  return __builtin_amdgcn_mfma_f32_32x32x16_bf16(a, b, c, 0, 0, 0);
}

static __device__ __forceinline__ u32 cvtpk(float lo, float hi_) {
  u32 r;
  asm("v_cvt_pk_bf16_f32 %0, %1, %2" : "=v"(r) : "v"(lo), "v"(hi_));
  return r;
}

static __device__ __forceinline__ void barrier_raw() {
  asm volatile("" ::: "memory");
  __builtin_amdgcn_s_barrier();
  asm volatile("" ::: "memory");
}

static __device__ __forceinline__ void gload_lds16(const u16* g, u16* l) {
  __builtin_amdgcn_global_load_lds((const __attribute__((address_space(1))) u32*)g,
                                   (__attribute__((address_space(3))) u32*)l, 16, 0, 0);
}

// ---------------- pack kernel ----------------
__global__ void pack_w_kernel(const float* __restrict__ Wq, const float* __restrict__ Wk,
                              const float* __restrict__ Wv, const float* __restrict__ Wo,
                              const float* __restrict__ bq, const float* __restrict__ bk,
                              const float* __restrict__ bv, u16* __restrict__ BTqkv,
                              u16* __restrict__ BTo, float* __restrict__ bqkv) {
  int idx = blockIdx.x * 256 + threadIdx.x;
  if (idx < 1536 * 512) {
    int n = idx >> 9, d = idx & 511;
    int t = n >> 9, rem = n & 511;
    int h = rem >> 6, e = rem & 63;
    const float* W = (t == 0) ? Wq : ((t == 1) ? Wk : Wv);
    float sc = (t == 0) ? SC_Q : 1.0f;
    BTqkv[idx] = f2bf(W[((size_t)h * 512 + d) * 64 + e] * sc);
  } else if (idx < 1536 * 512 + 512 * 512) {
    int j = idx - 1536 * 512;
    int n = j >> 9, d = j & 511;
    BTo[j] = f2bf(Wo[(size_t)d * 512 + n]);
  } else if (idx < 1536 * 512 + 512 * 512 + 1536) {
    int j = idx - (1536 * 512 + 512 * 512);
    int t = j >> 9, rem = j & 511;
    float v = (t == 0 ? bq : (t == 1 ? bk : bv))[rem];
    bqkv[j] = v * (t == 0 ? SC_Q : 1.0f);
  }
}

// ------- QKV GEMM (fused f32->bf16 A-pack), 128x64 tile; V -> Vtl transposed -------
// grid (x = m-tile:32, y = n-tile:24): same-m blocks share XCD -> A-panel L2 reuse.
__global__ __launch_bounds__(256) void gemm_qkv_kernel(const float* __restrict__ X,
                                                       const u16* __restrict__ BT,
                                                       const float* __restrict__ bias,
                                                       u16* __restrict__ QK,
                                                       u16* __restrict__ Vtl) {
  __shared__ __align__(16) u16 Al[2][128 * 64];
  __shared__ __align__(16) u16 Bl[2][64 * 64];
  const int K = 512;
  const int tid = threadIdx.x;
  const int w = tid >> 6, lane = tid & 63, g = lane >> 4, i = lane & 15;
  const int m0 = blockIdx.x * 128, n0 = blockIdx.y * 64;
  const int wr = (w >> 1) * 64, wc = (w & 1) * 32;

  f32x4 acc[4][2];
#pragma unroll
  for (int a = 0; a < 4; ++a)
#pragma unroll
    for (int b = 0; b < 2; ++b) acc[a][b] = f32x4{0.f, 0.f, 0.f, 0.f};

  const float* xg[4];
#pragma unroll
  for (int it = 0; it < 4; ++it) {
    const int slot = it * 256 + tid;
    xg[it] = X + (size_t)(m0 + (slot >> 3)) * K + (slot & 7) * 8;
  }
  const u16* bgp[2];
#pragma unroll
  for (int it = 0; it < 2; ++it) {
    const int slot = it * 256 + tid;
    bgp[it] = BT + (size_t)(n0 + (slot >> 3)) * K + (slot & 7) * 8;
  }

  float4 a0[4], a1[4];
#pragma unroll
  for (int it = 0; it < 4; ++it) {
    a0[it] = *reinterpret_cast<const float4*>(xg[it]);
    a1[it] = *reinterpret_cast<const float4*>(xg[it] + 4);
  }
#pragma unroll
  for (int it = 0; it < 2; ++it) gload_lds16(bgp[it], &Bl[0][(it * 256 + tid) * 8]);
  asm volatile("s_waitcnt vmcnt(2)" ::: "memory");
#pragma unroll
  for (int it = 0; it < 4; ++it) {
    u32x4 pk = {cvtpk(a0[it].x, a0[it].y), cvtpk(a0[it].z, a0[it].w),
                cvtpk(a1[it].x, a1[it].y), cvtpk(a1[it].z, a1[it].w)};
    *reinterpret_cast<u32x4*>(&Al[0][(it * 256 + tid) * 8]) = pk;
  }
  asm volatile("s_waitcnt lgkmcnt(0)" ::: "memory");

  int cur = 0;
  for (int t = 0; t < 8; ++t) {
    const int k0 = t * 64;
    if (t < 7) {
#pragma unroll
      for (int it = 0; it < 4; ++it) {
        a0[it] = *reinterpret_cast<const float4*>(xg[it] + k0 + 64);
        a1[it] = *reinterpret_cast<const float4*>(xg[it] + k0 + 68);
      }
#pragma unroll
      for (int it = 0; it < 2; ++it)
        gload_lds16(bgp[it] + k0 + 64, &Bl[cur ^ 1][(it * 256 + tid) * 8]);
      asm volatile("s_waitcnt vmcnt(10)" ::: "memory");
    } else {
      asm volatile("s_waitcnt vmcnt(0)" ::: "memory");
    }
    barrier_raw();
#pragma unroll
    for (int ks = 0; ks < 2; ++ks) {
      bf16x8 af[4], bf[2];
#pragma unroll
      for (int mf = 0; mf < 4; ++mf)
        af[mf] = *reinterpret_cast<const bf16x8*>(
            &Al[cur][(wr + mf * 16 + i) * 64 + ks * 32 + 8 * g]);
#pragma unroll
      for (int nf = 0; nf < 2; ++nf)
        bf[nf] = *reinterpret_cast<const bf16x8*>(
            &Bl[cur][(wc + nf * 16 + i) * 64 + ks * 32 + 8 * g]);
#pragma unroll
      for (int mf = 0; mf < 4; ++mf)
#pragma unroll
        for (int nf = 0; nf < 2; ++nf) acc[mf][nf] = mfma16(af[mf], bf[nf], acc[mf][nf]);
    }
    if (t < 7) {
      asm volatile("s_waitcnt vmcnt(2)" ::: "memory");
#pragma unroll
      for (int it = 0; it < 4; ++it) {
        u32x4 pk = {cvtpk(a0[it].x, a0[it].y), cvtpk(a0[it].z, a0[it].w),
                    cvtpk(a1[it].x, a1[it].y), cvtpk(a1[it].z, a1[it].w)};
        *reinterpret_cast<u32x4*>(&Al[cur ^ 1][(it * 256 + tid) * 8]) = pk;
      }
      asm volatile("s_waitcnt lgkmcnt(0)" ::: "memory");
    }
    barrier_raw();
    cur ^= 1;
  }

  if (n0 < 1024) {
#pragma unroll
    for (int nf = 0; nf < 2; ++nf) {
      const int col = n0 + wc + nf * 16 + i;
      const float bb = bias[col];
#pragma unroll
      for (int mf = 0; mf < 4; ++mf) {
#pragma unroll
        for (int r = 0; r < 4; ++r) {
          const int row = m0 + wr + mf * 16 + 4 * g + r;
          QK[(size_t)row * 1024 + col] = f2bf(acc[mf][nf][r] + bb);
        }
      }
    }
  } else {
    const int b = m0 >> 10;
    const int s0b = (m0 & 1023) + wr;
#pragma unroll
    for (int nf = 0; nf < 2; ++nf) {
      const int col = n0 + wc + nf * 16 + i;
      const float bb = bias[col];
      const int vcol = col - 1024;
      const size_t rowb = (size_t)(b * 512 + vcol) * 1024;
#pragma unroll
      for (int mf = 0; mf < 4; ++mf) {
        u16 pk[4];
#pragma unroll
        for (int r = 0; r < 4; ++r) pk[r] = f2bf(acc[mf][nf][r] + bb);
        const int ss = s0b + mf * 16 + 4 * g;
        *reinterpret_cast<uint2*>(&Vtl[rowb + ss]) = *reinterpret_cast<const uint2*>(pk);
      }
    }
  }
}

// ---------------- DENSE attention, all heads, 2-way KV split, KVBLK=64 ----------------
// grid (8 h, 8 qt, 8 zz=b*2+s); block keys [s*512, s*512+512); writes slot s
__global__ __launch_bounds__(256) void attn3_kernel(const u16* __restrict__ QK,
                                                    const u16* __restrict__ Vt,
                                                    u16* __restrict__ Opart16,
                                                    float* __restrict__ mlpart) {
  __shared__ __align__(16) u16 Kl[2][4096];
  __shared__ __align__(16) u16 Vl[2][4096];

  const int tid = threadIdx.x;
  const int w = tid >> 6, lane = tid & 63;
  const int col = lane & 31, hi = lane >> 5;
  const int h = blockIdx.x;  // 0..7 (XCD = flat%8 = h)
  const int zz = blockIdx.z;
  const int b = zz >> 1, s = zz & 1;
  const int bh = b * 8 + h;
  const int q0w = blockIdx.y * 128 + w * 32;
  const int kvlo = s * 512;
  const int hm = (h < 4) ? h : 4;
  const int band = 1 << hm;
  const int modm = (2 << hm) - 1;
  const int qrow = q0w + col;

  bf16x8 qf[4];
  const size_t qoff = (size_t)(b * 1024 + qrow) * 1024 + h * 64 + 8 * hi;
#pragma unroll
  for (int et = 0; et < 4; ++et)
    qf[et] = *reinterpret_cast<const bf16x8*>(QK + qoff + 16 * et);

  float bias[16];
#pragma unroll
  for (int r = 0; r < 16; ++r) {
    int c = (r & 3) + 8 * (r >> 2) + 4 * hi;
    bias[r] = (((qrow - c) & modm) == 0) ? 0.f : -1e30f;
  }

  f32x16 accO0 = {}, accO1 = {};
  float m_run = -1e30f, l_run = 0.f;

  const int slot0 = tid, slot1 = tid + 256;
  const int kj0 = slot0 >> 3, keb0 = (slot0 & 7) ^ (kj0 & 7);
  const int kj1 = slot1 >> 3, keb1 = (slot1 & 7) ^ (kj1 & 7);
  const u16* kg0 = QK + (size_t)(b * 1024 + kj0) * 1024 + 512 + h * 64 + keb0 * 8;
  const u16* kg1 = QK + (size_t)(b * 1024 + kj1) * 1024 + 512 + h * 64 + keb1 * 8;
  const u16* vg0 = Vt + (size_t)(bh * 64 + kj0) * 1024 + keb0 * 8;
  const u16* vg1 = Vt + (size_t)(bh * 64 + kj1) * 1024 + keb1 * 8;

#define STAGE3(bi, kv0)                                                 \
  do {                                                                  \
    gload_lds16(kg0 + (size_t)(kv0) * 1024, &Kl[bi][slot0 * 8]);        \
    gload_lds16(kg1 + (size_t)(kv0) * 1024, &Kl[bi][slot1 * 8]);        \
    gload_lds16(vg0 + (kv0), &Vl[bi][slot0 * 8]);                       \
    gload_lds16(vg1 + (kv0), &Vl[bi][slot1 * 8]);                       \
  } while (0)

  STAGE3(0, kvlo);
  int buf = 0;

  for (int t = 0; t < 8; ++t) {
    const int kv0 = kvlo + t * 64;
    if (t < 7) {
      STAGE3(buf ^ 1, kv0 + 64);
      asm volatile("s_waitcnt vmcnt(4)" ::: "memory");
    } else {
      asm volatile("s_waitcnt vmcnt(0)" ::: "memory");
    }
    barrier_raw();

    const u16* Kb = Kl[buf];
    const u16* Vb = Vl[buf];

    f32x16 s0 = {}, s1 = {};
    __builtin_amdgcn_s_setprio(1);
#pragma unroll
    for (int et = 0; et < 4; ++et) {
      const int sw = ((2 * et + hi) ^ (col & 7)) << 3;
      bf16x8 kf0 = *reinterpret_cast<const bf16x8*>(&Kb[col * 64 + sw]);
      bf16x8 kf1 = *reinterpret_cast<const bf16x8*>(&Kb[(col + 32) * 64 + sw]);
      s0 = mfma32(kf0, qf[et], s0);
      s1 = mfma32(kf1, qf[et], s1);
    }
    __builtin_amdgcn_s_setprio(0);

    float p[32];
    const int dq = qrow - kv0;
    const bool near = (q0w <= kv0 + 63 + band) && (kv0 <= q0w + 31 + band);
    if (near) {
#pragma unroll
      for (int r = 0; r < 16; ++r) {
        const int c = (r & 3) + 8 * (r >> 2) + 4 * hi;
        int d0 = dq - c, d1 = d0 - 32;
        d0 = d0 < 0 ? -d0 : d0;
        d1 = d1 < 0 ? -d1 : d1;
        p[r] = (d0 <= band) ? s0[r] : s0[r] + bias[r];
        p[r + 16] = (d1 <= band) ? s1[r] : s1[r] + bias[r];
      }
    } else {
#pragma unroll
      for (int r = 0; r < 16; ++r) {
        p[r] = s0[r] + bias[r];
        p[r + 16] = s1[r] + bias[r];
      }
    }

    float tr[16];
#pragma unroll
    for (int j = 0; j < 16; ++j) tr[j] = fmaxf(p[j], p[j + 16]);
#pragma unroll
    for (int st = 8; st >= 1; st >>= 1)
#pragma unroll
      for (int j = 0; j < st; ++j) tr[j] = fmaxf(tr[j], tr[j + st]);
    float mu = fmaxf(tr[0], __shfl_xor(tr[0], 32));

    if (__any(mu > m_run + 8.f)) {
      float mn = fmaxf(m_run, mu);
      float corr = EXP2F(m_run - mn);
      m_run = mn;
      l_run *= corr;
#pragma unroll
      for (int j = 0; j < 16; ++j) {
        accO0[j] *= corr;
        accO1[j] *= corr;
      }
    }

#pragma unroll
    for (int j = 0; j < 32; ++j) p[j] = EXP2F(p[j] - m_run);
    float ts[16];
#pragma unroll
    for (int j = 0; j < 16; ++j) ts[j] = p[j] + p[j + 16];
#pragma unroll
    for (int st = 8; st >= 1; st >>= 1)
#pragma unroll
      for (int j = 0; j < st; ++j) ts[j] += ts[j + st];
    l_run += ts[0] + __shfl_xor(ts[0], 32);

    // P -> A-frag: 2 shfls/slice (send what the partner needs)
#pragma unroll
    for (int kt = 0; kt < 4; ++kt) {
      const float* pp = (kt < 2) ? p : p + 16;
      const int R = (kt & 1) * 8;
      u32 A0 = cvtpk(pp[R + 0], pp[R + 1]);
      u32 A1 = cvtpk(pp[R + 2], pp[R + 3]);
      u32 B0 = cvtpk(pp[R + 4], pp[R + 5]);
      u32 B1 = cvtpk(pp[R + 6], pp[R + 7]);
      // hi=0 lane needs partner's A-words; hi=1 lane needs partner's B-words.
      u32 t0 = __shfl_xor(hi ? A0 : B0, 32);
      u32 t1 = __shfl_xor(hi ? A1 : B1, 32);
      u32 w0 = hi ? t0 : A0;
      u32 w1 = hi ? t1 : A1;
      u32 w2 = hi ? B0 : t0;
      u32 w3 = hi ? B1 : t1;
      u32x4 pu = {w0, w1, w2, w3};
      bf16x8 paf = __builtin_bit_cast(bf16x8, pu);
      const int jb = 2 * kt + hi;
      __builtin_amdgcn_s_setprio(1);
      {
        const int erow = col;
        bf16x8 vf = *reinterpret_cast<const bf16x8*>(&Vb[erow * 64 + ((jb ^ (erow & 7)) << 3)]);
        accO0 = mfma32(paf, vf, accO0);
      }
      {
        const int erow = 32 + col;
        bf16x8 vf = *reinterpret_cast<const bf16x8*>(&Vb[erow * 64 + ((jb ^ (erow & 7)) << 3)]);
        accO1 = mfma32(paf, vf, accO1);
      }
      __builtin_amdgcn_s_setprio(0);
    }

    barrier_raw();
    buf ^= 1;
  }
#undef STAGE3

  const size_t obase = (size_t)(s * 32 + bh) * 1024 + q0w;
  if (lane < 32) {
    float2 ml2 = {m_run, l_run};
    *reinterpret_cast<float2*>(&mlpart[(obase + col) * 2]) = ml2;
  }
#pragma unroll
  for (int r = 0; r < 16; ++r) {
    const int c = (r & 3) + 8 * (r >> 2) + 4 * hi;
    u16* orow = Opart16 + (obase + c) * 64;
    orow[col] = f2bf(accO0[r]);
    orow[32 + col] = f2bf(accO1[r]);
  }
}

// ------- out projection with FUSED 2-way combine: out = combine(Opart,ml) @ BTo^T + bo -------
// 64x64 tile, grid (x = m-tile:64, y = n-tile:8): same-m blocks share XCD.
__global__ __launch_bounds__(256) void gemm_out_kernel(const u16* __restrict__ Opart16,
                                                       const float* __restrict__ mlpart,
                                                       const u16* __restrict__ BT,
                                                       const float* __restrict__ bias,
                                                       float* __restrict__ Cf) {
  __shared__ __align__(16) u16 Al[2][64 * 64];
  __shared__ __align__(16) u16 Bl[2][64 * 64];
  const int K = 512;
  const int tid = threadIdx.x;
  const int w = tid >> 6, lane = tid & 63, g = lane >> 4, i = lane & 15;
  const int m0 = blockIdx.x * 64, n0 = blockIdx.y * 64;
  const int wr = (w >> 1) * 32, wc = (w & 1) * 32;

  f32x4 acc[2][2];
#pragma unroll
  for (int a = 0; a < 2; ++a)
#pragma unroll
    for (int b = 0; b < 2; ++b) acc[a][b] = f32x4{0.f, 0.f, 0.f, 0.f};

  size_t R0[2];
  int cb8[2];
#pragma unroll
  for (int it = 0; it < 2; ++it) {
    const int slot = it * 256 + tid;
    const int r_in = slot >> 3;
    cb8[it] = (slot & 7) * 8;
    const int grow = m0 + r_in;
    const int b2 = grow >> 10, qr = grow & 1023;
    R0[it] = (size_t)(b2 * 8) * 1024 + qr;  // + (s2*32 + t)*1024
  }
  const u16* bgp[2];
#pragma unroll
  for (int it = 0; it < 2; ++it) {
    const int slot = it * 256 + tid;
    bgp[it] = BT + (size_t)(n0 + (slot >> 3)) * K + (slot & 7) * 8;
  }

  uint4 aO[2][2];
  float2 aml[2][2];

#define LOAD_A(t)                                                                     \
  do {                                                                                \
    _Pragma("unroll") for (int it = 0; it < 2; ++it) {                                \
      _Pragma("unroll") for (int s2 = 0; s2 < 2; ++s2) {                              \
        const size_t rb = R0[it] + (size_t)(s2 * 32 + (t)) * 1024;                    \
        aO[it][s2] = *reinterpret_cast<const uint4*>(&Opart16[rb * 64 + cb8[it]]);    \
        aml[it][s2] = *reinterpret_cast<const float2*>(&mlpart[rb * 2]);              \
      }                                                                               \
    }                                                                                 \
  } while (0)

#define COMBINE_WRITE(bi)                                                             \
  do {                                                                                \
    _Pragma("unroll") for (int it = 0; it < 2; ++it) {                                \
      const float mA = aml[it][0].x, lA = aml[it][0].y;                               \
      const float mB = aml[it][1].x, lB = aml[it][1].y;                               \
      const float M2 = fmaxf(mA, mB);                                                 \
      const float wA = EXP2F(mA - M2), wB = EXP2F(mB - M2);                           \
      const float inv = 1.0f / (lA * wA + lB * wB);                                   \
      const float sA = wA * inv, sB = wB * inv;                                       \
      const u32* oa = reinterpret_cast<const u32*>(&aO[it][0]);                       \
      const u32* ob = reinterpret_cast<const u32*>(&aO[it][1]);                       \
      float c[8];                                                                     \
      _Pragma("unroll") for (int q = 0; q < 4; ++q) {                                 \
        c[2 * q] = bf2f((u16)(oa[q] & 0xffff)) * sA + bf2f((u16)(ob[q] & 0xffff)) * sB; \
        c[2 * q + 1] = bf2f((u16)(oa[q] >> 16)) * sA + bf2f((u16)(ob[q] >> 16)) * sB; \
      }                                                                               \
      u32x4 pk = {cvtpk(c[0], c[1]), cvtpk(c[2], c[3]), cvtpk(c[4], c[5]),            \
                  cvtpk(c[6], c[7])};                                                 \
      *reinterpret_cast<u32x4*>(&Al[bi][(it * 256 + tid) * 8]) = pk;                  \
    }                                                                                 \
  } while (0)

  // prologue: A(t=0) regs + B(k0=0) glds
  LOAD_A(0);
#pragma unroll
  for (int it = 0; it < 2; ++it) gload_lds16(bgp[it], &Bl[0][(it * 256 + tid) * 8]);
  asm volatile("s_waitcnt vmcnt(2)" ::: "memory");  // 8 A-group loads done (2 B flying)
  COMBINE_WRITE(0);
  asm volatile("s_waitcnt lgkmcnt(0)" ::: "memory");

  int cur = 0;
  for (int t = 0; t < 8; ++t) {
    if (t < 7) {
      LOAD_A(t + 1);
#pragma unroll
      for (int it = 0; it < 2; ++it)
        gload_lds16(bgp[it] + t * 64 + 64, &Bl[cur ^ 1][(it * 256 + tid) * 8]);
      asm volatile("s_waitcnt vmcnt(10)" ::: "memory");  // cur B done; 8A+2B in flight
    } else {
      asm volatile("s_waitcnt vmcnt(0)" ::: "memory");
    }
    barrier_raw();
#pragma unroll
    for (int ks = 0; ks < 2; ++ks) {
      bf16x8 af[2], bf[2];
#pragma unroll
      for (int mf = 0; mf < 2; ++mf)
        af[mf] = *reinterpret_cast<const bf16x8*>(
            &Al[cur][(wr + mf * 16 + i) * 64 + ks * 32 + 8 * g]);
#pragma unroll
      for (int nf = 0; nf < 2; ++nf)
        bf[nf] = *reinterpret_cast<const bf16x8*>(
            &Bl[cur][(wc + nf * 16 + i) * 64 + ks * 32 + 8 * g]);
#pragma unroll
      for (int mf = 0; mf < 2; ++mf)
#pragma unroll
        for (int nf = 0; nf < 2; ++nf) acc[mf][nf] = mfma16(af[mf], bf[nf], acc[mf][nf]);
    }
    if (t < 7) {
      asm volatile("s_waitcnt vmcnt(2)" ::: "memory");  // A(t+1) regs landed
      COMBINE_WRITE(cur ^ 1);
      asm volatile("s_waitcnt lgkmcnt(0)" ::: "memory");
    }
    barrier_raw();
    cur ^= 1;
  }
#undef LOAD_A
#undef COMBINE_WRITE

#pragma unroll
  for (int nf = 0; nf < 2; ++nf) {
    const int col = n0 + wc + nf * 16 + i;
    const float bb = bias[col];
#pragma unroll
    for (int mf = 0; mf < 2; ++mf) {
#pragma unroll
      for (int r = 0; r < 4; ++r) {
        const int row = m0 + wr + mf * 16 + 4 * g + r;
        Cf[(size_t)row * 512 + col] = acc[mf][nf][r] + bb;
      }
    }
  }
}

// ---------------- launch ----------------
extern "C" void kernel_launch(void* const* d_in, const int* in_sizes, int n_in,
                              void* d_out, int out_size, void* d_ws, size_t ws_size,
                              hipStream_t stream) {
  const float* x = (const float*)d_in[0];
  const float* Wq = (const float*)d_in[1];
  const float* bq = (const float*)d_in[2];
  const float* Wk = (const float*)d_in[3];
  const float* bk = (const float*)d_in[4];
  const float* Wv = (const float*)d_in[5];
  const float* bv = (const float*)d_in[6];
  const float* Wo = (const float*)d_in[7];
  const float* bo = (const float*)d_in[8];
  float* out = (float*)d_out;

  char* ws = (char*)d_ws;
  u16* BTqkv = (u16*)(ws + (4u << 20));     // 1.5 MB [1536][512]
  u16* BTo = (u16*)(ws + (6u << 20));       // 0.5 MB [512][512]
  float* bqkv = (float*)(ws + (7u << 20));  // 6 KB
  u16* QK = (u16*)(ws + (8u << 20));        // 8 MB  [4096][1024] (Q | K)
  u16* Vtl = (u16*)(ws + (21u << 20));      // 4 MB  [b*512+e][seq]
  u16* Opart16 = (u16*)(ws + (32u << 20));  // 8 MB  [2 slots][32 bh][1024][64]
  float* mlpart = (float*)(ws + (56u << 20));  // 512 KB [2 slots][32 bh][1024][2]

  const int NW = 1536 * 512 + 512 * 512 + 1536;
  pack_w_kernel<<<(NW + 255) / 256, 256, 0, stream>>>(Wq, Wk, Wv, Wo, bq, bk, bv, BTqkv,
                                                      BTo, bqkv);

  // QKV projection: grid x=m-tiles for per-XCD A-panel reuse
  gemm_qkv_kernel<<<dim3(32, 24), 256, 0, stream>>>(x, BTqkv, bqkv, QK, Vtl);

  // attention: dense all heads, 2-way KV split, 64-key tiles
  attn3_kernel<<<dim3(8, 8, 8), 256, 0, stream>>>(QK, Vtl, Opart16, mlpart);

  // output projection with fused 2-way split-combine: grid x=m-tiles
  gemm_out_kernel<<<dim3(64, 8), 256, 0, stream>>>(Opart16, mlpart, BTo, bo, out);
}

// Round 20
// 62.993 us; speedup vs baseline: 1.2700x; 1.0090x over previous
//
#include <hip/hip_runtime.h>

typedef unsigned short u16;
typedef unsigned int u32;
typedef __attribute__((ext_vector_type(8))) __bf16 bf16x8;
typedef __attribute__((ext_vector_type(4))) float f32x4;
typedef __attribute__((ext_vector_type(16))) float f32x16;
typedef __attribute__((ext_vector_type(4))) u32 u32x4;

#if __has_builtin(__builtin_amdgcn_exp2f)
#define EXP2F(x) __builtin_amdgcn_exp2f(x)
#else
#define EXP2F(x) exp2f(x)
#endif

// 0.125 (1/sqrt(64)) * log2(e): folded into Wq/bq so scores are in exp2 domain
#define SC_Q 0.18033688011112042f

static __device__ __forceinline__ u16 f2bf(float f) {
  unsigned u = __builtin_bit_cast(unsigned, f);
  u += 0x7fffu + ((u >> 16) & 1u);
  return (u16)(u >> 16);
}
static __device__ __forceinline__ float bf2f(u16 v) {
  return __builtin_bit_cast(float, (u32)v << 16);
}

static __device__ __forceinline__ f32x4 mfma16(bf16x8 a, bf16x8 b, f32x4 c) {
  return __builtin_amdgcn_mfma_f32_16x16x32_bf16(a, b, c, 0, 0, 0);
}
static __device__ __forceinline__ f32x16 mfma32(bf16x8 a, bf16x8 b, f32x16 c) {
  return __builtin_amdgcn_mfma_f32_32x32x16_bf16(a, b, c, 0, 0, 0);
}

static __device__ __forceinline__ u32 cvtpk(float lo, float hi_) {
  u32 r;
  asm("v_cvt_pk_bf16_f32 %0, %1, %2" : "=v"(r) : "v"(lo), "v"(hi_));
  return r;
}

static __device__ __forceinline__ void barrier_raw() {
  asm volatile("" ::: "memory");
  __builtin_amdgcn_s_barrier();
  asm volatile("" ::: "memory");
}

static __device__ __forceinline__ void gload_lds16(const u16* g, u16* l) {
  __builtin_amdgcn_global_load_lds((const __attribute__((address_space(1))) u32*)g,
                                   (__attribute__((address_space(3))) u32*)l, 16, 0, 0);
}

// ---------------- pack kernel ----------------
__global__ void pack_w_kernel(const float* __restrict__ Wq, const float* __restrict__ Wk,
                              const float* __restrict__ Wv, const float* __restrict__ Wo,
                              const float* __restrict__ bq, const float* __restrict__ bk,
                              const float* __restrict__ bv, u16* __restrict__ BTqkv,
                              u16* __restrict__ BTo, float* __restrict__ bqkv) {
  int idx = blockIdx.x * 256 + threadIdx.x;
  if (idx < 1536 * 512) {
    int n = idx >> 9, d = idx & 511;
    int t = n >> 9, rem = n & 511;
    int h = rem >> 6, e = rem & 63;
    const float* W = (t == 0) ? Wq : ((t == 1) ? Wk : Wv);
    float sc = (t == 0) ? SC_Q : 1.0f;
    BTqkv[idx] = f2bf(W[((size_t)h * 512 + d) * 64 + e] * sc);
  } else if (idx < 1536 * 512 + 512 * 512) {
    int j = idx - 1536 * 512;
    int n = j >> 9, d = j & 511;
    BTo[j] = f2bf(Wo[(size_t)d * 512 + n]);
  } else if (idx < 1536 * 512 + 512 * 512 + 1536) {
    int j = idx - (1536 * 512 + 512 * 512);
    int t = j >> 9, rem = j & 511;
    float v = (t == 0 ? bq : (t == 1 ? bk : bv))[rem];
    bqkv[j] = v * (t == 0 ? SC_Q : 1.0f);
  }
}

// ------- QKV GEMM (fused f32->bf16 A-pack), 128x64 tile; V -> Vtl transposed -------
// grid (x = m-tile:32, y = n-tile:24): same-m blocks share XCD -> A-panel L2 reuse.
__global__ __launch_bounds__(256) void gemm_qkv_kernel(const float* __restrict__ X,
                                                       const u16* __restrict__ BT,
                                                       const float* __restrict__ bias,
                                                       u16* __restrict__ QK,
                                                       u16* __restrict__ Vtl) {
  __shared__ __align__(16) u16 Al[2][128 * 64];
  __shared__ __align__(16) u16 Bl[2][64 * 64];
  const int K = 512;
  const int tid = threadIdx.x;
  const int w = tid >> 6, lane = tid & 63, g = lane >> 4, i = lane & 15;
  const int m0 = blockIdx.x * 128, n0 = blockIdx.y * 64;
  const int wr = (w >> 1) * 64, wc = (w & 1) * 32;

  f32x4 acc[4][2];
#pragma unroll
  for (int a = 0; a < 4; ++a)
#pragma unroll
    for (int b = 0; b < 2; ++b) acc[a][b] = f32x4{0.f, 0.f, 0.f, 0.f};

  const float* xg[4];
#pragma unroll
  for (int it = 0; it < 4; ++it) {
    const int slot = it * 256 + tid;
    xg[it] = X + (size_t)(m0 + (slot >> 3)) * K + (slot & 7) * 8;
  }
  const u16* bgp[2];
#pragma unroll
  for (int it = 0; it < 2; ++it) {
    const int slot = it * 256 + tid;
    bgp[it] = BT + (size_t)(n0 + (slot >> 3)) * K + (slot & 7) * 8;
  }

  float4 a0[4], a1[4];
#pragma unroll
  for (int it = 0; it < 4; ++it) {
    a0[it] = *reinterpret_cast<const float4*>(xg[it]);
    a1[it] = *reinterpret_cast<const float4*>(xg[it] + 4);
  }
#pragma unroll
  for (int it = 0; it < 2; ++it) gload_lds16(bgp[it], &Bl[0][(it * 256 + tid) * 8]);
  asm volatile("s_waitcnt vmcnt(2)" ::: "memory");
#pragma unroll
  for (int it = 0; it < 4; ++it) {
    u32x4 pk = {cvtpk(a0[it].x, a0[it].y), cvtpk(a0[it].z, a0[it].w),
                cvtpk(a1[it].x, a1[it].y), cvtpk(a1[it].z, a1[it].w)};
    *reinterpret_cast<u32x4*>(&Al[0][(it * 256 + tid) * 8]) = pk;
  }
  asm volatile("s_waitcnt lgkmcnt(0)" ::: "memory");

  int cur = 0;
  for (int t = 0; t < 8; ++t) {
    const int k0 = t * 64;
    if (t < 7) {
#pragma unroll
      for (int it = 0; it < 4; ++it) {
        a0[it] = *reinterpret_cast<const float4*>(xg[it] + k0 + 64);
        a1[it] = *reinterpret_cast<const float4*>(xg[it] + k0 + 68);
      }
#pragma unroll
      for (int it = 0; it < 2; ++it)
        gload_lds16(bgp[it] + k0 + 64, &Bl[cur ^ 1][(it * 256 + tid) * 8]);
      asm volatile("s_waitcnt vmcnt(10)" ::: "memory");
    } else {
      asm volatile("s_waitcnt vmcnt(0)" ::: "memory");
    }
    barrier_raw();
#pragma unroll
    for (int ks = 0; ks < 2; ++ks) {
      bf16x8 af[4], bf[2];
#pragma unroll
      for (int mf = 0; mf < 4; ++mf)
        af[mf] = *reinterpret_cast<const bf16x8*>(
            &Al[cur][(wr + mf * 16 + i) * 64 + ks * 32 + 8 * g]);
#pragma unroll
      for (int nf = 0; nf < 2; ++nf)
        bf[nf] = *reinterpret_cast<const bf16x8*>(
            &Bl[cur][(wc + nf * 16 + i) * 64 + ks * 32 + 8 * g]);
#pragma unroll
      for (int mf = 0; mf < 4; ++mf)
#pragma unroll
        for (int nf = 0; nf < 2; ++nf) acc[mf][nf] = mfma16(af[mf], bf[nf], acc[mf][nf]);
    }
    if (t < 7) {
      asm volatile("s_waitcnt vmcnt(2)" ::: "memory");
#pragma unroll
      for (int it = 0; it < 4; ++it) {
        u32x4 pk = {cvtpk(a0[it].x, a0[it].y), cvtpk(a0[it].z, a0[it].w),
                    cvtpk(a1[it].x, a1[it].y), cvtpk(a1[it].z, a1[it].w)};
        *reinterpret_cast<u32x4*>(&Al[cur ^ 1][(it * 256 + tid) * 8]) = pk;
      }
      asm volatile("s_waitcnt lgkmcnt(0)" ::: "memory");
    }
    barrier_raw();
    cur ^= 1;
  }

  if (n0 < 1024) {
#pragma unroll
    for (int nf = 0; nf < 2; ++nf) {
      const int col = n0 + wc + nf * 16 + i;
      const float bb = bias[col];
#pragma unroll
      for (int mf = 0; mf < 4; ++mf) {
#pragma unroll
        for (int r = 0; r < 4; ++r) {
          const int row = m0 + wr + mf * 16 + 4 * g + r;
          QK[(size_t)row * 1024 + col] = f2bf(acc[mf][nf][r] + bb);
        }
      }
    }
  } else {
    const int b = m0 >> 10;
    const int s0b = (m0 & 1023) + wr;
#pragma unroll
    for (int nf = 0; nf < 2; ++nf) {
      const int col = n0 + wc + nf * 16 + i;
      const float bb = bias[col];
      const int vcol = col - 1024;
      const size_t rowb = (size_t)(b * 512 + vcol) * 1024;
#pragma unroll
      for (int mf = 0; mf < 4; ++mf) {
        u16 pk[4];
#pragma unroll
        for (int r = 0; r < 4; ++r) pk[r] = f2bf(acc[mf][nf][r] + bb);
        const int ss = s0b + mf * 16 + 4 * g;
        *reinterpret_cast<uint2*>(&Vtl[rowb + ss]) = *reinterpret_cast<const uint2*>(pk);
      }
    }
  }
}

// ---------------- DENSE attention, all heads, 2-way KV split, KVBLK=64 ----------------
// grid (8 h, 8 qt, 8 zz=b*2+s); block keys [s*512, s*512+512); writes slot s
// 3-buffer rotation, ONE barrier per tile (barrier-first: write of (t+2)%3 only after
// barrier t, which all waves pass only after computing tile t-1 = prior occupant).
__global__ __launch_bounds__(256) void attn3_kernel(const u16* __restrict__ QK,
                                                    const u16* __restrict__ Vt,
                                                    u16* __restrict__ Opart16,
                                                    float* __restrict__ mlpart) {
  __shared__ __align__(16) u16 Kl[3][4096];
  __shared__ __align__(16) u16 Vl[3][4096];

  const int tid = threadIdx.x;
  const int w = tid >> 6, lane = tid & 63;
  const int col = lane & 31, hi = lane >> 5;
  const int h = blockIdx.x;  // 0..7 (XCD = flat%8 = h)
  const int zz = blockIdx.z;
  const int b = zz >> 1, s = zz & 1;
  const int bh = b * 8 + h;
  const int q0w = blockIdx.y * 128 + w * 32;
  const int kvlo = s * 512;
  const int hm = (h < 4) ? h : 4;
  const int band = 1 << hm;
  const int modm = (2 << hm) - 1;
  const int qrow = q0w + col;

  bf16x8 qf[4];
  const size_t qoff = (size_t)(b * 1024 + qrow) * 1024 + h * 64 + 8 * hi;
#pragma unroll
  for (int et = 0; et < 4; ++et)
    qf[et] = *reinterpret_cast<const bf16x8*>(QK + qoff + 16 * et);

  float bias[16];
#pragma unroll
  for (int r = 0; r < 16; ++r) {
    int c = (r & 3) + 8 * (r >> 2) + 4 * hi;
    bias[r] = (((qrow - c) & modm) == 0) ? 0.f : -1e30f;
  }

  f32x16 accO0 = {}, accO1 = {};
  float m_run = -1e30f, l_run = 0.f;

  const int slot0 = tid, slot1 = tid + 256;
  const int kj0 = slot0 >> 3, keb0 = (slot0 & 7) ^ (kj0 & 7);
  const int kj1 = slot1 >> 3, keb1 = (slot1 & 7) ^ (kj1 & 7);
  const u16* kg0 = QK + (size_t)(b * 1024 + kj0) * 1024 + 512 + h * 64 + keb0 * 8;
  const u16* kg1 = QK + (size_t)(b * 1024 + kj1) * 1024 + 512 + h * 64 + keb1 * 8;
  const u16* vg0 = Vt + (size_t)(bh * 64 + kj0) * 1024 + keb0 * 8;
  const u16* vg1 = Vt + (size_t)(bh * 64 + kj1) * 1024 + keb1 * 8;

#define STAGE3(bi, kv0)                                                 \
  do {                                                                  \
    gload_lds16(kg0 + (size_t)(kv0) * 1024, &Kl[bi][slot0 * 8]);        \
    gload_lds16(kg1 + (size_t)(kv0) * 1024, &Kl[bi][slot1 * 8]);        \
    gload_lds16(vg0 + (kv0), &Vl[bi][slot0 * 8]);                       \
    gload_lds16(vg1 + (kv0), &Vl[bi][slot1 * 8]);                       \
  } while (0)

  // prologue: tiles 0 and 1 in flight
  STAGE3(0, kvlo);
  STAGE3(1, kvlo + 64);

#pragma unroll
  for (int t = 0; t < 8; ++t) {
    const int bi = t % 3;
    const int kv0 = kvlo + t * 64;

    barrier_raw();  // all waves done computing tile t-1 -> safe to overwrite (t+2)%3
    if (t < 6) {
      STAGE3((t + 2) % 3, kv0 + 128);
      asm volatile("s_waitcnt vmcnt(8)" ::: "memory");  // tile t's 4 loads complete
    } else if (t == 6) {
      asm volatile("s_waitcnt vmcnt(4)" ::: "memory");
    } else {
      asm volatile("s_waitcnt vmcnt(0)" ::: "memory");
    }

    const u16* Kb = Kl[bi];
    const u16* Vb = Vl[bi];

    f32x16 s0 = {}, s1 = {};
    __builtin_amdgcn_s_setprio(1);
#pragma unroll
    for (int et = 0; et < 4; ++et) {
      const int sw = ((2 * et + hi) ^ (col & 7)) << 3;
      bf16x8 kf0 = *reinterpret_cast<const bf16x8*>(&Kb[col * 64 + sw]);
      bf16x8 kf1 = *reinterpret_cast<const bf16x8*>(&Kb[(col + 32) * 64 + sw]);
      s0 = mfma32(kf0, qf[et], s0);
      s1 = mfma32(kf1, qf[et], s1);
    }
    __builtin_amdgcn_s_setprio(0);

    float p[32];
    const int dq = qrow - kv0;
    const bool near = (q0w <= kv0 + 63 + band) && (kv0 <= q0w + 31 + band);
    if (near) {
#pragma unroll
      for (int r = 0; r < 16; ++r) {
        const int c = (r & 3) + 8 * (r >> 2) + 4 * hi;
        int d0 = dq - c, d1 = d0 - 32;
        d0 = d0 < 0 ? -d0 : d0;
        d1 = d1 < 0 ? -d1 : d1;
        p[r] = (d0 <= band) ? s0[r] : s0[r] + bias[r];
        p[r + 16] = (d1 <= band) ? s1[r] : s1[r] + bias[r];
      }
    } else {
#pragma unroll
      for (int r = 0; r < 16; ++r) {
        p[r] = s0[r] + bias[r];
        p[r + 16] = s1[r] + bias[r];
      }
    }

    float tr[16];
#pragma unroll
    for (int j = 0; j < 16; ++j) tr[j] = fmaxf(p[j], p[j + 16]);
#pragma unroll
    for (int st = 8; st >= 1; st >>= 1)
#pragma unroll
      for (int j = 0; j < st; ++j) tr[j] = fmaxf(tr[j], tr[j + st]);
    float mu = fmaxf(tr[0], __shfl_xor(tr[0], 32));

    if (__any(mu > m_run + 8.f)) {
      float mn = fmaxf(m_run, mu);
      float corr = EXP2F(m_run - mn);
      m_run = mn;
      l_run *= corr;
#pragma unroll
      for (int j = 0; j < 16; ++j) {
        accO0[j] *= corr;
        accO1[j] *= corr;
      }
    }

#pragma unroll
    for (int j = 0; j < 32; ++j) p[j] = EXP2F(p[j] - m_run);
    float ts[16];
#pragma unroll
    for (int j = 0; j < 16; ++j) ts[j] = p[j] + p[j + 16];
#pragma unroll
    for (int st = 8; st >= 1; st >>= 1)
#pragma unroll
      for (int j = 0; j < st; ++j) ts[j] += ts[j + st];
    l_run += ts[0] + __shfl_xor(ts[0], 32);

    // P -> A-frag: 2 shfls/slice (send what the partner needs)
#pragma unroll
    for (int kt = 0; kt < 4; ++kt) {
      const float* pp = (kt < 2) ? p : p + 16;
      const int R = (kt & 1) * 8;
      u32 A0 = cvtpk(pp[R + 0], pp[R + 1]);
      u32 A1 = cvtpk(pp[R + 2], pp[R + 3]);
      u32 B0 = cvtpk(pp[R + 4], pp[R + 5]);
      u32 B1 = cvtpk(pp[R + 6], pp[R + 7]);
      // hi=0 lane needs partner's A-words; hi=1 lane needs partner's B-words.
      u32 t0 = __shfl_xor(hi ? A0 : B0, 32);
      u32 t1 = __shfl_xor(hi ? A1 : B1, 32);
      u32 w0 = hi ? t0 : A0;
      u32 w1 = hi ? t1 : A1;
      u32 w2 = hi ? B0 : t0;
      u32 w3 = hi ? B1 : t1;
      u32x4 pu = {w0, w1, w2, w3};
      bf16x8 paf = __builtin_bit_cast(bf16x8, pu);
      const int jb = 2 * kt + hi;
      __builtin_amdgcn_s_setprio(1);
      {
        const int erow = col;
        bf16x8 vf = *reinterpret_cast<const bf16x8*>(&Vb[erow * 64 + ((jb ^ (erow & 7)) << 3)]);
        accO0 = mfma32(paf, vf, accO0);
      }
      {
        const int erow = 32 + col;
        bf16x8 vf = *reinterpret_cast<const bf16x8*>(&Vb[erow * 64 + ((jb ^ (erow & 7)) << 3)]);
        accO1 = mfma32(paf, vf, accO1);
      }
      __builtin_amdgcn_s_setprio(0);
    }
  }
#undef STAGE3

  const size_t obase = (size_t)(s * 32 + bh) * 1024 + q0w;
  if (lane < 32) {
    float2 ml2 = {m_run, l_run};
    *reinterpret_cast<float2*>(&mlpart[(obase + col) * 2]) = ml2;
  }
#pragma unroll
  for (int r = 0; r < 16; ++r) {
    const int c = (r & 3) + 8 * (r >> 2) + 4 * hi;
    u16* orow = Opart16 + (obase + c) * 64;
    orow[col] = f2bf(accO0[r]);
    orow[32 + col] = f2bf(accO1[r]);
  }
}

// ------- out projection with FUSED 2-way combine: out = combine(Opart,ml) @ BTo^T + bo -------
// 64x64 tile, grid (x = m-tile:64, y = n-tile:8): same-m blocks share XCD.
__global__ __launch_bounds__(256) void gemm_out_kernel(const u16* __restrict__ Opart16,
                                                       const float* __restrict__ mlpart,
                                                       const u16* __restrict__ BT,
                                                       const float* __restrict__ bias,
                                                       float* __restrict__ Cf) {
  __shared__ __align__(16) u16 Al[2][64 * 64];
  __shared__ __align__(16) u16 Bl[2][64 * 64];
  const int K = 512;
  const int tid = threadIdx.x;
  const int w = tid >> 6, lane = tid & 63, g = lane >> 4, i = lane & 15;
  const int m0 = blockIdx.x * 64, n0 = blockIdx.y * 64;
  const int wr = (w >> 1) * 32, wc = (w & 1) * 32;

  f32x4 acc[2][2];
#pragma unroll
  for (int a = 0; a < 2; ++a)
#pragma unroll
    for (int b = 0; b < 2; ++b) acc[a][b] = f32x4{0.f, 0.f, 0.f, 0.f};

  size_t R0[2];
  int cb8[2];
#pragma unroll
  for (int it = 0; it < 2; ++it) {
    const int slot = it * 256 + tid;
    const int r_in = slot >> 3;
    cb8[it] = (slot & 7) * 8;
    const int grow = m0 + r_in;
    const int b2 = grow >> 10, qr = grow & 1023;
    R0[it] = (size_t)(b2 * 8) * 1024 + qr;  // + (s2*32 + t)*1024
  }
  const u16* bgp[2];
#pragma unroll
  for (int it = 0; it < 2; ++it) {
    const int slot = it * 256 + tid;
    bgp[it] = BT + (size_t)(n0 + (slot >> 3)) * K + (slot & 7) * 8;
  }

  uint4 aO[2][2];
  float2 aml[2][2];

#define LOAD_A(t)                                                                     \
  do {                                                                                \
    _Pragma("unroll") for (int it = 0; it < 2; ++it) {                                \
      _Pragma("unroll") for (int s2 = 0; s2 < 2; ++s2) {                              \
        const size_t rb = R0[it] + (size_t)(s2 * 32 + (t)) * 1024;                    \
        aO[it][s2] = *reinterpret_cast<const uint4*>(&Opart16[rb * 64 + cb8[it]]);    \
        aml[it][s2] = *reinterpret_cast<const float2*>(&mlpart[rb * 2]);              \
      }                                                                               \
    }                                                                                 \
  } while (0)

#define COMBINE_WRITE(bi)                                                             \
  do {                                                                                \
    _Pragma("unroll") for (int it = 0; it < 2; ++it) {                                \
      const float mA = aml[it][0].x, lA = aml[it][0].y;                               \
      const float mB = aml[it][1].x, lB = aml[it][1].y;                               \
      const float M2 = fmaxf(mA, mB);                                                 \
      const float wA = EXP2F(mA - M2), wB = EXP2F(mB - M2);                           \
      const float inv = 1.0f / (lA * wA + lB * wB);                                   \
      const float sA = wA * inv, sB = wB * inv;                                       \
      const u32* oa = reinterpret_cast<const u32*>(&aO[it][0]);                       \
      const u32* ob = reinterpret_cast<const u32*>(&aO[it][1]);                       \
      float c[8];                                                                     \
      _Pragma("unroll") for (int q = 0; q < 4; ++q) {                                 \
        c[2 * q] = bf2f((u16)(oa[q] & 0xffff)) * sA + bf2f((u16)(ob[q] & 0xffff)) * sB; \
        c[2 * q + 1] = bf2f((u16)(oa[q] >> 16)) * sA + bf2f((u16)(ob[q] >> 16)) * sB; \
      }                                                                               \
      u32x4 pk = {cvtpk(c[0], c[1]), cvtpk(c[2], c[3]), cvtpk(c[4], c[5]),            \
                  cvtpk(c[6], c[7])};                                                 \
      *reinterpret_cast<u32x4*>(&Al[bi][(it * 256 + tid) * 8]) = pk;                  \
    }                                                                                 \
  } while (0)

  // prologue: A(t=0) regs + B(k0=0) glds
  LOAD_A(0);
#pragma unroll
  for (int it = 0; it < 2; ++it) gload_lds16(bgp[it], &Bl[0][(it * 256 + tid) * 8]);
  asm volatile("s_waitcnt vmcnt(2)" ::: "memory");  // 8 A-group loads done (2 B flying)
  COMBINE_WRITE(0);
  asm volatile("s_waitcnt lgkmcnt(0)" ::: "memory");

  int cur = 0;
  for (int t = 0; t < 8; ++t) {
    if (t < 7) {
      LOAD_A(t + 1);
#pragma unroll
      for (int it = 0; it < 2; ++it)
        gload_lds16(bgp[it] + t * 64 + 64, &Bl[cur ^ 1][(it * 256 + tid) * 8]);
      asm volatile("s_waitcnt vmcnt(10)" ::: "memory");  // cur B done; 8A+2B in flight
    } else {
      asm volatile("s_waitcnt vmcnt(0)" ::: "memory");
    }
    barrier_raw();
#pragma unroll
    for (int ks = 0; ks < 2; ++ks) {
      bf16x8 af[2], bf[2];
#pragma unroll
      for (int mf = 0; mf < 2; ++mf)
        af[mf] = *reinterpret_cast<const bf16x8*>(
            &Al[cur][(wr + mf * 16 + i) * 64 + ks * 32 + 8 * g]);
#pragma unroll
      for (int nf = 0; nf < 2; ++nf)
        bf[nf] = *reinterpret_cast<const bf16x8*>(
            &Bl[cur][(wc + nf * 16 + i) * 64 + ks * 32 + 8 * g]);
#pragma unroll
      for (int mf = 0; mf < 2; ++mf)
#pragma unroll
        for (int nf = 0; nf < 2; ++nf) acc[mf][nf] = mfma16(af[mf], bf[nf], acc[mf][nf]);
    }
    if (t < 7) {
      asm volatile("s_waitcnt vmcnt(2)" ::: "memory");  // A(t+1) regs landed
      COMBINE_WRITE(cur ^ 1);
      asm volatile("s_waitcnt lgkmcnt(0)" ::: "memory");
    }
    barrier_raw();
    cur ^= 1;
  }
#undef LOAD_A
#undef COMBINE_WRITE

#pragma unroll
  for (int nf = 0; nf < 2; ++nf) {
    const int col = n0 + wc + nf * 16 + i;
    const float bb = bias[col];
#pragma unroll
    for (int mf = 0; mf < 2; ++mf) {
#pragma unroll
      for (int r = 0; r < 4; ++r) {
        const int row = m0 + wr + mf * 16 + 4 * g + r;
        Cf[(size_t)row * 512 + col] = acc[mf][nf][r] + bb;
      }
    }
  }
}

// ---------------- launch ----------------
extern "C" void kernel_launch(void* const* d_in, const int* in_sizes, int n_in,
                              void* d_out, int out_size, void* d_ws, size_t ws_size,
                              hipStream_t stream) {
  const float* x = (const float*)d_in[0];
  const float* Wq = (const float*)d_in[1];
  const float* bq = (const float*)d_in[2];
  const float* Wk = (const float*)d_in[3];
  const float* bk = (const float*)d_in[4];
  const float* Wv = (const float*)d_in[5];
  const float* bv = (const float*)d_in[6];
  const float* Wo = (const float*)d_in[7];
  const float* bo = (const float*)d_in[8];
  float* out = (float*)d_out;

  char* ws = (char*)d_ws;
  u16* BTqkv = (u16*)(ws + (4u << 20));     // 1.5 MB [1536][512]
  u16* BTo = (u16*)(ws + (6u << 20));       // 0.5 MB [512][512]
  float* bqkv = (float*)(ws + (7u << 20));  // 6 KB
  u16* QK = (u16*)(ws + (8u << 20));        // 8 MB  [4096][1024] (Q | K)
  u16* Vtl = (u16*)(ws + (21u << 20));      // 4 MB  [b*512+e][seq]
  u16* Opart16 = (u16*)(ws + (32u << 20));  // 8 MB  [2 slots][32 bh][1024][64]
  float* mlpart = (float*)(ws + (56u << 20));  // 512 KB [2 slots][32 bh][1024][2]

  const int NW = 1536 * 512 + 512 * 512 + 1536;
  pack_w_kernel<<<(NW + 255) / 256, 256, 0, stream>>>(Wq, Wk, Wv, Wo, bq, bk, bv, BTqkv,
                                                      BTo, bqkv);

  // QKV projection: grid x=m-tiles for per-XCD A-panel reuse
  gemm_qkv_kernel<<<dim3(32, 24), 256, 0, stream>>>(x, BTqkv, bqkv, QK, Vtl);

  // attention: dense all heads, 2-way KV split, 64-key tiles, 3-buffer 1-barrier loop
  attn3_kernel<<<dim3(8, 8, 8), 256, 0, stream>>>(QK, Vtl, Opart16, mlpart);

  // output projection with fused 2-way split-combine: grid x=m-tiles
  gemm_out_kernel<<<dim3(64, 8), 256, 0, stream>>>(Opart16, mlpart, BTo, bo, out);
}